// Round 5
// baseline (330.523 us; speedup 1.0000x reference)
//
#include <hip/hip_runtime.h>

#define KCLS 19
#define CCH 64
#define HW (512*512)
#define NPIX (4*HW)

// K1 geometry: lane = channel
#define NWAVE 4
#define WPX 256                 // pixels per wave
#define BPX (NWAVE * WPX)       // 1024 pixels per block
#define NBLK (NPIX / BPX)       // 1024 blocks
#define NBLK3 1024

// ws float offsets
#define WS_COUNTS  0      // 19
#define WS_SUMS    32     // [k*64+c], 1216
#define WS_VARSUM  1280   // 19
#define WS_CENTERS 1312   // [k*64+c], 1216
#define WS_SCAL    2560   // 0: loss_dis, 1: loss_reg, 2: n_valid
#define WS_DONE1   2568   // int ticket for k1
#define WS_DONE3   2569   // int ticket for k3
#define WS_NFLOATS 2576

__device__ __forceinline__ void ldsAdd(float* p, float v) { unsafeAtomicAdd(p, v); }
__device__ __forceinline__ float atomRead(float* p) { return unsafeAtomicAdd(p, 0.0f); }

// ---------------- K0: zero workspace ----------------
__global__ __launch_bounds__(256) void k0_zero(float* __restrict__ ws) {
    for (int i = threadIdx.x; i < WS_NFLOATS; i += 256) ws[i] = 0.0f;
}

// ---------------- K1: counts + per-class per-channel sums, then (last block) centers/push/reg ----------------
// block 256 (4 waves); wave handles 256 contiguous pixels; lane = channel.
// bins[w][c*21 + k] is lane-private -> plain RMW, no atomics, 2 lanes/bank.
__global__ __launch_bounds__(256) void k1_sums(const float* __restrict__ pred,
                                               const int* __restrict__ tgt,
                                               float* __restrict__ ws) {
    const int t = threadIdx.x;
    const int l = t & 63;            // lane -> channel
    const int w = t >> 6;            // wave id
    const int base_px = blockIdx.x * BPX;
    const int n = base_px / HW;
    const int hwb = base_px - n * HW;

    __shared__ unsigned labw[BPX / 4];        // 1 KB packed u8 labels
    __shared__ float bins[NWAVE][64 * 21];    // 21.5 KB, per-wave per-lane bins
    __shared__ float cnt[16 * 21];            // 1.3 KB, 16-replica count hist
    __shared__ int isLast;

    float* bw = bins[w];
    #pragma unroll
    for (int k = 0; k < 21; ++k) bw[l * 21 + k] = 0.0f;
    for (int i = t; i < 16 * 21; i += 256) cnt[i] = 0.0f;
    __syncthreads();

    // stage labels (packed u8) + count histogram via ds_add_f32 (16 replicas)
    {
        int4 L = ((const int4*)(tgt + base_px))[t];
        labw[t] = (unsigned)(L.x & 0xFF) | ((unsigned)(L.y & 0xFF) << 8) |
                  ((unsigned)(L.z & 0xFF) << 16) | ((unsigned)(L.w & 0xFF) << 24);
        float* cr = &cnt[(t & 15) * 21];
        ldsAdd(&cr[L.x & 31], 1.0f);
        ldsAdd(&cr[L.y & 31], 1.0f);
        ldsAdd(&cr[L.z & 31], 1.0f);
        ldsAdd(&cr[L.w & 31], 1.0f);
    }
    __syncthreads();

    // main loop: per pixel, all 64 lanes update their own bin row
    const float4* src = (const float4*)(pred + (size_t)(n * CCH + l) * HW + hwb + w * WPX);
    const unsigned* lwp = &labw[w * 64];
    float* br = &bw[l * 21];
    for (int i = 0; i < WPX / 4; ++i) {
        const unsigned lw = lwp[i];          // uniform -> broadcast
        const float4 v = src[i];
        const int b0 = lw & 31, b1 = (lw >> 8) & 31, b2 = (lw >> 16) & 31, b3 = (lw >> 24) & 31;
        br[b0] += v.x;
        br[b1] += v.y;
        br[b2] += v.z;
        br[b3] += v.w;
    }
    __syncthreads();

    // flush
    for (int idx = t; idx < KCLS * CCH; idx += 256) {
        const int k = idx >> 6, c = idx & 63;
        float s = bins[0][c * 21 + k] + bins[1][c * 21 + k] +
                  bins[2][c * 21 + k] + bins[3][c * 21 + k];
        unsafeAtomicAdd(&ws[WS_SUMS + idx], s);
    }
    if (t < KCLS) {
        float s = 0.0f;
        #pragma unroll
        for (int r = 0; r < 16; ++r) s += cnt[r * 21 + t];
        unsafeAtomicAdd(&ws[WS_COUNTS + t], s);
    }

    // ---- last-block epilogue: centers + push + reg (formerly k2) ----
    __threadfence();
    __syncthreads();
    if (t == 0) isLast = (atomicAdd((int*)(ws + WS_DONE1), 1) == NBLK - 1);
    __syncthreads();
    if (!isLast) return;

    float* ct = &bins[0][0];      // reuse: 1280 floats, ct[c*20 + k]
    float* cntS = cnt;            // reuse: 19
    float* acc = cnt + 20;        // reuse: 2
    if (t < KCLS) cntS[t] = atomRead(&ws[WS_COUNTS + t]);
    if (t < 2) acc[t] = 0.0f;
    __syncthreads();

    for (int i = t; i < KCLS * CCH; i += 256) {
        int k = i >> 6, c = i & 63;
        float ctr = atomRead(&ws[WS_SUMS + i]) / fmaxf(cntS[k], 1.0f);
        ws[WS_CENTERS + i] = ctr;
        ct[c * 20 + k] = ctr;
    }
    __syncthreads();

    for (int p = t; p < KCLS * KCLS; p += 256) {
        int i = p / KCLS, j = p % KCLS;
        if (i != j && cntS[i] > 20.0f && cntS[j] > 20.0f) {
            float sq = 0.0f;
            #pragma unroll 8
            for (int c = 0; c < CCH; ++c) {
                float d = ct[c * 20 + i] - ct[c * 20 + j];
                sq = fmaf(d, d, sq);
            }
            float pd = sqrtf(sq);
            float r = 3.0f - pd;        // 2*DELTA - pd
            if (r > 0.0f) ldsAdd(&acc[0], r * r);
        }
    }
    if (t < KCLS && cntS[t] > 20.0f) {
        float sq = 0.0f;
        #pragma unroll 8
        for (int c = 0; c < CCH; ++c) { float v = ct[c * 20 + t]; sq = fmaf(v, v, sq); }
        ldsAdd(&acc[1], sqrtf(sq));
    }
    __syncthreads();
    if (t == 0) {
        float nv = 0.0f;
        for (int k = 0; k < KCLS; ++k) nv += (cntS[k] > 20.0f) ? 1.0f : 0.0f;
        ws[WS_SCAL + 0] = acc[0] / fmaxf(nv * (nv - 1.0f), 1.0f);
        ws[WS_SCAL + 1] = acc[1] / fmaxf(nv, 1.0f);
        ws[WS_SCAL + 2] = nv;
    }
}

// ---------------- K3: per-pixel pull term, then (last block) final combine ----------------
// grid: 1024 chunks of 1024 pixels, block 256 (4 px/thread)
__global__ __launch_bounds__(256) void k3_var(const float* __restrict__ pred,
                                              const int* __restrict__ tgt,
                                              float* __restrict__ ws,
                                              float* __restrict__ out) {
    const int t = threadIdx.x;
    const int cid = blockIdx.x;          // 1024
    const int n = cid >> 8;              // HW/1024 = 256 chunks per image
    const int hwb = (cid & 255) * 1024;

    __shared__ float ct[CCH * 20];       // ct[c*20 + k]
    __shared__ float varh[80];
    __shared__ int isLast;

    for (int i = t; i < CCH * 20; i += 256) {
        int c = i / 20, k = i % 20;
        ct[i] = (k < KCLS) ? ws[WS_CENTERS + k * CCH + c] : 0.0f;
    }
    if (t < 80) varh[t] = 0.0f;

    const int4 l0 = ((const int4*)(tgt + n * HW + hwb))[t];
    const int lab0 = l0.x, lab1 = l0.y, lab2 = l0.z, lab3 = l0.w;
    float a0 = 0.0f, a1 = 0.0f, a2 = 0.0f, a3 = 0.0f;
    __syncthreads();

    const float* base = pred + (size_t)n * CCH * HW + hwb;
    #pragma unroll 4
    for (int c = 0; c < CCH; ++c) {
        float4 v = ((const float4*)(base + (size_t)c * HW))[t];
        const float* row = &ct[c * 20];
        float m0 = row[lab0], m1 = row[lab1], m2 = row[lab2], m3 = row[lab3];
        float d0 = v.x - m0, d1 = v.y - m1, d2 = v.z - m2, d3 = v.w - m3;
        a0 = fmaf(d0, d0, a0);
        a1 = fmaf(d1, d1, a1);
        a2 = fmaf(d2, d2, a2);
        a3 = fmaf(d3, d3, a3);
    }

    const int rep = (t & 3) * KCLS;
    {
        float d, r;
        d = sqrtf(fmaxf(a0, 1e-12f)); r = d - 0.5f; if (r > 0.0f) ldsAdd(&varh[rep + lab0], r * r);
        d = sqrtf(fmaxf(a1, 1e-12f)); r = d - 0.5f; if (r > 0.0f) ldsAdd(&varh[rep + lab1], r * r);
        d = sqrtf(fmaxf(a2, 1e-12f)); r = d - 0.5f; if (r > 0.0f) ldsAdd(&varh[rep + lab2], r * r);
        d = sqrtf(fmaxf(a3, 1e-12f)); r = d - 0.5f; if (r > 0.0f) ldsAdd(&varh[rep + lab3], r * r);
    }
    __syncthreads();
    if (t < KCLS) {
        float s = varh[t] + varh[19 + t] + varh[38 + t] + varh[57 + t];
        unsafeAtomicAdd(&ws[WS_VARSUM + t], s);
    }

    // ---- last-block epilogue: final combine (formerly k4) ----
    __threadfence();
    __syncthreads();
    if (t == 0) isLast = (atomicAdd((int*)(ws + WS_DONE3), 1) == NBLK3 - 1);
    __syncthreads();
    if (!isLast) return;

    if (t < 64) {
        float v = 0.0f;
        if (t < KCLS) {
            float c = atomRead(&ws[WS_COUNTS + t]);
            float vs = atomRead(&ws[WS_VARSUM + t]);
            if (c > 20.0f) v = vs / fmaxf(c, 1.0f);
        }
        #pragma unroll
        for (int s = 32; s > 0; s >>= 1) v += __shfl_down(v, s);
        if (t == 0) {
            float nv = ws[WS_SCAL + 2];
            out[0] = v / fmaxf(nv, 1.0f) + ws[WS_SCAL + 0] + 0.001f * ws[WS_SCAL + 1];
        }
    }
}

extern "C" void kernel_launch(void* const* d_in, const int* in_sizes, int n_in,
                              void* d_out, int out_size, void* d_ws, size_t ws_size,
                              hipStream_t stream) {
    const float* pred = (const float*)d_in[0];
    const int* tgt = (const int*)d_in[1];
    float* ws = (float*)d_ws;
    float* out = (float*)d_out;

    hipLaunchKernelGGL(k0_zero, dim3(1), dim3(256), 0, stream, ws);
    hipLaunchKernelGGL(k1_sums, dim3(NBLK), dim3(256), 0, stream, pred, tgt, ws);
    hipLaunchKernelGGL(k3_var, dim3(NBLK3), dim3(256), 0, stream, pred, tgt, ws, out);
}

// Round 6
// 146.105 us; speedup vs baseline: 2.2622x; 2.2622x over previous
//
#include <hip/hip_runtime.h>

#define KCLS 19
#define CCH 64
#define HW (512*512)
#define NPIX (4*HW)

// K1 geometry: lane = channel
#define NWAVE 4
#define WPX 256                 // pixels per wave
#define BPX (NWAVE * WPX)       // 1024 pixels per block
#define NBLK (NPIX / BPX)       // 1024 blocks
#define NBLK3 1024

// ws float offsets
#define WS_COUNTS  0      // 19
#define WS_SUMS    32     // [k*64+c], 1216
#define WS_VARSUM  1280   // 19
#define WS_CENTERS 1312   // [k*64+c], 1216
#define WS_SCAL    2560   // 0: loss_dis, 1: loss_reg, 2: n_valid
#define WS_NFLOATS 2576

__device__ __forceinline__ void ldsAdd(float* p, float v) { unsafeAtomicAdd(p, v); }

// ---------------- K0: zero workspace ----------------
__global__ __launch_bounds__(256) void k0_zero(float* __restrict__ ws) {
    for (int i = threadIdx.x; i < WS_NFLOATS; i += 256) ws[i] = 0.0f;
}

// ---------------- K1: per-class counts + per-class per-channel sums ----------------
// block 256 (4 waves); wave handles 256 contiguous pixels; lane = channel.
// bins[w][c*21 + k] is lane-private -> plain RMW, no atomics, 2 lanes/bank.
__global__ __launch_bounds__(256) void k1_sums(const float* __restrict__ pred,
                                               const int* __restrict__ tgt,
                                               float* __restrict__ ws) {
    const int t = threadIdx.x;
    const int l = t & 63;            // lane -> channel
    const int w = t >> 6;            // wave id
    const int base_px = blockIdx.x * BPX;
    const int n = base_px / HW;
    const int hwb = base_px - n * HW;

    __shared__ unsigned labw[BPX / 4];        // 1 KB packed u8 labels
    __shared__ float bins[NWAVE][64 * 21];    // 21.5 KB, per-wave per-lane bins
    __shared__ float cnt[16 * 21];            // 1.3 KB, 16-replica count hist

    float* bw = bins[w];
    #pragma unroll
    for (int k = 0; k < 21; ++k) bw[l * 21 + k] = 0.0f;
    for (int i = t; i < 16 * 21; i += 256) cnt[i] = 0.0f;
    __syncthreads();

    // stage labels (packed u8) + count histogram via ds_add_f32 (16 replicas)
    {
        int4 L = ((const int4*)(tgt + base_px))[t];
        labw[t] = (unsigned)(L.x & 0xFF) | ((unsigned)(L.y & 0xFF) << 8) |
                  ((unsigned)(L.z & 0xFF) << 16) | ((unsigned)(L.w & 0xFF) << 24);
        float* cr = &cnt[(t & 15) * 21];
        ldsAdd(&cr[L.x & 31], 1.0f);
        ldsAdd(&cr[L.y & 31], 1.0f);
        ldsAdd(&cr[L.z & 31], 1.0f);
        ldsAdd(&cr[L.w & 31], 1.0f);
    }
    __syncthreads();

    // main loop: per pixel, all 64 lanes update their own bin row
    const float4* src = (const float4*)(pred + (size_t)(n * CCH + l) * HW + hwb + w * WPX);
    const unsigned* lwp = &labw[w * 64];
    float* br = &bw[l * 21];
    for (int i = 0; i < WPX / 4; ++i) {
        const unsigned lw = lwp[i];          // uniform -> broadcast
        const float4 v = src[i];
        const int b0 = lw & 31, b1 = (lw >> 8) & 31, b2 = (lw >> 16) & 31, b3 = (lw >> 24) & 31;
        br[b0] += v.x;
        br[b1] += v.y;
        br[b2] += v.z;
        br[b3] += v.w;
    }
    __syncthreads();

    // flush: sums (1216 values) and counts (19)
    for (int idx = t; idx < KCLS * CCH; idx += 256) {
        const int k = idx >> 6, c = idx & 63;
        float s = bins[0][c * 21 + k] + bins[1][c * 21 + k] +
                  bins[2][c * 21 + k] + bins[3][c * 21 + k];
        unsafeAtomicAdd(&ws[WS_SUMS + idx], s);
    }
    if (t < KCLS) {
        float s = 0.0f;
        #pragma unroll
        for (int r = 0; r < 16; ++r) s += cnt[r * 21 + t];
        unsafeAtomicAdd(&ws[WS_COUNTS + t], s);
    }
}

// ---------------- K2: centers, valid, push (pairwise) + reg terms ----------------
__global__ __launch_bounds__(256) void k2_centers(float* __restrict__ ws) {
    __shared__ float ct[CCH * 20];     // transposed, padded: ct[c*20 + k]
    __shared__ float cntS[KCLS];
    __shared__ float acc[2];           // 0: dis numerator, 1: reg numerator
    const int t = threadIdx.x;
    if (t < KCLS) cntS[t] = ws[WS_COUNTS + t];
    if (t < 2) acc[t] = 0.0f;
    __syncthreads();

    for (int i = t; i < KCLS * CCH; i += 256) {
        int k = i >> 6, c = i & 63;
        float ctr = ws[WS_SUMS + i] / fmaxf(cntS[k], 1.0f);
        ws[WS_CENTERS + i] = ctr;
        ct[c * 20 + k] = ctr;
    }
    __syncthreads();

    for (int p = t; p < KCLS * KCLS; p += 256) {
        int i = p / KCLS, j = p % KCLS;
        if (i != j && cntS[i] > 20.0f && cntS[j] > 20.0f) {
            float sq = 0.0f;
            #pragma unroll 8
            for (int c = 0; c < CCH; ++c) {
                float d = ct[c * 20 + i] - ct[c * 20 + j];
                sq = fmaf(d, d, sq);
            }
            float pd = sqrtf(sq);
            float r = 3.0f - pd;        // 2*DELTA - pd
            if (r > 0.0f) atomicAdd(&acc[0], r * r);
        }
    }
    if (t < KCLS && cntS[t] > 20.0f) {
        float sq = 0.0f;
        #pragma unroll 8
        for (int c = 0; c < CCH; ++c) { float v = ct[c * 20 + t]; sq = fmaf(v, v, sq); }
        atomicAdd(&acc[1], sqrtf(sq));
    }
    __syncthreads();
    if (t == 0) {
        float nv = 0.0f;
        for (int k = 0; k < KCLS; ++k) nv += (cntS[k] > 20.0f) ? 1.0f : 0.0f;
        ws[WS_SCAL + 0] = acc[0] / fmaxf(nv * (nv - 1.0f), 1.0f);
        ws[WS_SCAL + 1] = acc[1] / fmaxf(nv, 1.0f);
        ws[WS_SCAL + 2] = nv;
    }
}

// ---------------- K3: per-pixel pull (variance) term ----------------
// grid: 1024 chunks of 1024 pixels, block 256 (4 px/thread)
__global__ __launch_bounds__(256) void k3_var(const float* __restrict__ pred,
                                              const int* __restrict__ tgt,
                                              float* __restrict__ ws) {
    const int t = threadIdx.x;
    const int cid = blockIdx.x;          // 1024
    const int n = cid >> 8;              // HW/1024 = 256 chunks per image
    const int hwb = (cid & 255) * 1024;

    __shared__ float ct[CCH * 20];       // ct[c*20 + k]: 19 consecutive banks -> conflict-free
    __shared__ float varh[80];

    for (int i = t; i < CCH * 20; i += 256) {
        int c = i / 20, k = i % 20;
        ct[i] = (k < KCLS) ? ws[WS_CENTERS + k * CCH + c] : 0.0f;
    }
    if (t < 80) varh[t] = 0.0f;

    const int4 l0 = ((const int4*)(tgt + n * HW + hwb))[t];
    const int lab0 = l0.x, lab1 = l0.y, lab2 = l0.z, lab3 = l0.w;
    float a0 = 0.0f, a1 = 0.0f, a2 = 0.0f, a3 = 0.0f;
    __syncthreads();

    const float* base = pred + (size_t)n * CCH * HW + hwb;
    #pragma unroll 4
    for (int c = 0; c < CCH; ++c) {
        float4 v = ((const float4*)(base + (size_t)c * HW))[t];
        const float* row = &ct[c * 20];
        float m0 = row[lab0], m1 = row[lab1], m2 = row[lab2], m3 = row[lab3];
        float d0 = v.x - m0, d1 = v.y - m1, d2 = v.z - m2, d3 = v.w - m3;
        a0 = fmaf(d0, d0, a0);
        a1 = fmaf(d1, d1, a1);
        a2 = fmaf(d2, d2, a2);
        a3 = fmaf(d3, d3, a3);
    }

    const int rep = (t & 3) * KCLS;
    {
        float d, r;
        d = sqrtf(fmaxf(a0, 1e-12f)); r = d - 0.5f; if (r > 0.0f) ldsAdd(&varh[rep + lab0], r * r);
        d = sqrtf(fmaxf(a1, 1e-12f)); r = d - 0.5f; if (r > 0.0f) ldsAdd(&varh[rep + lab1], r * r);
        d = sqrtf(fmaxf(a2, 1e-12f)); r = d - 0.5f; if (r > 0.0f) ldsAdd(&varh[rep + lab2], r * r);
        d = sqrtf(fmaxf(a3, 1e-12f)); r = d - 0.5f; if (r > 0.0f) ldsAdd(&varh[rep + lab3], r * r);
    }
    __syncthreads();
    if (t < KCLS) {
        float s = varh[t] + varh[19 + t] + varh[38 + t] + varh[57 + t];
        unsafeAtomicAdd(&ws[WS_VARSUM + t], s);
    }
}

// ---------------- K4: final combine ----------------
__global__ void k4_final(const float* __restrict__ ws, float* __restrict__ out) {
    const int t = threadIdx.x;   // 64 threads
    float v = 0.0f;
    if (t < KCLS) {
        float c = ws[WS_COUNTS + t];
        if (c > 20.0f) v = ws[WS_VARSUM + t] / fmaxf(c, 1.0f);
    }
    #pragma unroll
    for (int s = 32; s > 0; s >>= 1) v += __shfl_down(v, s);
    if (t == 0) {
        float nv = ws[WS_SCAL + 2];
        out[0] = v / fmaxf(nv, 1.0f) + ws[WS_SCAL + 0] + 0.001f * ws[WS_SCAL + 1];
    }
}

extern "C" void kernel_launch(void* const* d_in, const int* in_sizes, int n_in,
                              void* d_out, int out_size, void* d_ws, size_t ws_size,
                              hipStream_t stream) {
    const float* pred = (const float*)d_in[0];
    const int* tgt = (const int*)d_in[1];
    float* ws = (float*)d_ws;
    float* out = (float*)d_out;

    hipLaunchKernelGGL(k0_zero, dim3(1), dim3(256), 0, stream, ws);
    hipLaunchKernelGGL(k1_sums, dim3(NBLK), dim3(256), 0, stream, pred, tgt, ws);
    hipLaunchKernelGGL(k2_centers, dim3(1), dim3(256), 0, stream, ws);
    hipLaunchKernelGGL(k3_var, dim3(1024), dim3(256), 0, stream, pred, tgt, ws);
    hipLaunchKernelGGL(k4_final, dim3(1), dim3(64), 0, stream, ws, out);
}

// Round 7
// 144.676 us; speedup vs baseline: 2.2846x; 1.0099x over previous
//
#include <hip/hip_runtime.h>

#define KCLS 19
#define CCH 64
#define HW (512*512)
#define NPIX (4*HW)

// K1 geometry: lane = channel
#define NWAVE 4
#define WPX 256                 // pixels per wave
#define BPX (NWAVE * WPX)       // 1024 pixels per block
#define NBLK (NPIX / BPX)       // 1024 blocks
#define NBLK3 1024

// ws float offsets
#define WS_COUNTS  0      // 19
#define WS_SUMS    32     // [k*64+c], 1216
#define WS_VARSUM  1280   // 19
#define WS_CENTERS 1312   // [k*64+c], 1216
#define WS_SCAL    2560   // 0: loss_dis, 1: loss_reg, 2: n_valid
#define WS_NFLOATS 2576

__device__ __forceinline__ void ldsAdd(float* p, float v) { unsafeAtomicAdd(p, v); }

// ---------------- K0: zero workspace ----------------
__global__ __launch_bounds__(256) void k0_zero(float* __restrict__ ws) {
    for (int i = threadIdx.x; i < WS_NFLOATS; i += 256) ws[i] = 0.0f;
}

// ---------------- K1: per-class counts + per-class per-channel sums ----------------
// block 256 (4 waves); wave handles 256 contiguous pixels; lane = channel.
// bins[w][c*21 + k] is lane-private -> plain RMW, no atomics, 2 lanes/bank.
// Reads pred FORWARD (the previous replay's k3 leaves the beginning of pred warm in L3).
__global__ __launch_bounds__(256) void k1_sums(const float* __restrict__ pred,
                                               const int* __restrict__ tgt,
                                               float* __restrict__ ws) {
    const int t = threadIdx.x;
    const int l = t & 63;            // lane -> channel
    const int w = t >> 6;            // wave id
    const int base_px = blockIdx.x * BPX;
    const int n = base_px / HW;
    const int hwb = base_px - n * HW;

    __shared__ unsigned labw[BPX / 4];        // 1 KB packed u8 labels
    __shared__ float bins[NWAVE][64 * 21];    // 21.5 KB, per-wave per-lane bins
    __shared__ float cnt[16 * 21];            // 1.3 KB, 16-replica count hist

    float* bw = bins[w];
    #pragma unroll
    for (int k = 0; k < 21; ++k) bw[l * 21 + k] = 0.0f;
    for (int i = t; i < 16 * 21; i += 256) cnt[i] = 0.0f;
    __syncthreads();

    // stage labels (packed u8) + count histogram via ds_add_f32 (16 replicas)
    {
        int4 L = ((const int4*)(tgt + base_px))[t];
        labw[t] = (unsigned)(L.x & 0xFF) | ((unsigned)(L.y & 0xFF) << 8) |
                  ((unsigned)(L.z & 0xFF) << 16) | ((unsigned)(L.w & 0xFF) << 24);
        float* cr = &cnt[(t & 15) * 21];
        ldsAdd(&cr[L.x & 31], 1.0f);
        ldsAdd(&cr[L.y & 31], 1.0f);
        ldsAdd(&cr[L.z & 31], 1.0f);
        ldsAdd(&cr[L.w & 31], 1.0f);
    }
    __syncthreads();

    // main loop: per pixel, all 64 lanes update their own bin row
    const float4* src = (const float4*)(pred + (size_t)(n * CCH + l) * HW + hwb + w * WPX);
    const unsigned* lwp = &labw[w * 64];
    float* br = &bw[l * 21];
    for (int i = 0; i < WPX / 4; ++i) {
        const unsigned lw = lwp[i];          // uniform -> broadcast
        const float4 v = src[i];
        const int b0 = lw & 31, b1 = (lw >> 8) & 31, b2 = (lw >> 16) & 31, b3 = (lw >> 24) & 31;
        br[b0] += v.x;
        br[b1] += v.y;
        br[b2] += v.z;
        br[b3] += v.w;
    }
    __syncthreads();

    // flush: sums (1216 values) and counts (19)
    for (int idx = t; idx < KCLS * CCH; idx += 256) {
        const int k = idx >> 6, c = idx & 63;
        float s = bins[0][c * 21 + k] + bins[1][c * 21 + k] +
                  bins[2][c * 21 + k] + bins[3][c * 21 + k];
        unsafeAtomicAdd(&ws[WS_SUMS + idx], s);
    }
    if (t < KCLS) {
        float s = 0.0f;
        #pragma unroll
        for (int r = 0; r < 16; ++r) s += cnt[r * 21 + t];
        unsafeAtomicAdd(&ws[WS_COUNTS + t], s);
    }
}

// ---------------- K2: centers, valid, push (pairwise) + reg terms ----------------
__global__ __launch_bounds__(256) void k2_centers(float* __restrict__ ws) {
    __shared__ float ct[CCH * 20];     // transposed, padded: ct[c*20 + k]
    __shared__ float cntS[KCLS];
    __shared__ float acc[2];           // 0: dis numerator, 1: reg numerator
    const int t = threadIdx.x;
    if (t < KCLS) cntS[t] = ws[WS_COUNTS + t];
    if (t < 2) acc[t] = 0.0f;
    __syncthreads();

    for (int i = t; i < KCLS * CCH; i += 256) {
        int k = i >> 6, c = i & 63;
        float ctr = ws[WS_SUMS + i] / fmaxf(cntS[k], 1.0f);
        ws[WS_CENTERS + i] = ctr;
        ct[c * 20 + k] = ctr;
    }
    __syncthreads();

    for (int p = t; p < KCLS * KCLS; p += 256) {
        int i = p / KCLS, j = p % KCLS;
        if (i != j && cntS[i] > 20.0f && cntS[j] > 20.0f) {
            float sq = 0.0f;
            #pragma unroll 8
            for (int c = 0; c < CCH; ++c) {
                float d = ct[c * 20 + i] - ct[c * 20 + j];
                sq = fmaf(d, d, sq);
            }
            float pd = sqrtf(sq);
            float r = 3.0f - pd;        // 2*DELTA - pd
            if (r > 0.0f) atomicAdd(&acc[0], r * r);
        }
    }
    if (t < KCLS && cntS[t] > 20.0f) {
        float sq = 0.0f;
        #pragma unroll 8
        for (int c = 0; c < CCH; ++c) { float v = ct[c * 20 + t]; sq = fmaf(v, v, sq); }
        atomicAdd(&acc[1], sqrtf(sq));
    }
    __syncthreads();
    if (t == 0) {
        float nv = 0.0f;
        for (int k = 0; k < KCLS; ++k) nv += (cntS[k] > 20.0f) ? 1.0f : 0.0f;
        ws[WS_SCAL + 0] = acc[0] / fmaxf(nv * (nv - 1.0f), 1.0f);
        ws[WS_SCAL + 1] = acc[1] / fmaxf(nv, 1.0f);
        ws[WS_SCAL + 2] = nv;
    }
}

// ---------------- K3: per-pixel pull (variance) term ----------------
// grid: 1024 chunks of 1024 pixels, block 256 (4 px/thread).
// Block order REVERSED: k1 streamed pred forward, so the tail of pred is warm
// in the 256 MB L3 — start there and chase the MRU data backwards.
__global__ __launch_bounds__(256) void k3_var(const float* __restrict__ pred,
                                              const int* __restrict__ tgt,
                                              float* __restrict__ ws) {
    const int t = threadIdx.x;
    const int cid = (NBLK3 - 1) - blockIdx.x;   // reversed
    const int n = cid >> 8;              // HW/1024 = 256 chunks per image
    const int hwb = (cid & 255) * 1024;

    __shared__ float ct[CCH * 20];       // ct[c*20 + k]: 19 consecutive banks -> conflict-free
    __shared__ float varh[80];

    for (int i = t; i < CCH * 20; i += 256) {
        int c = i / 20, k = i % 20;
        ct[i] = (k < KCLS) ? ws[WS_CENTERS + k * CCH + c] : 0.0f;
    }
    if (t < 80) varh[t] = 0.0f;

    const int4 l0 = ((const int4*)(tgt + n * HW + hwb))[t];
    const int lab0 = l0.x, lab1 = l0.y, lab2 = l0.z, lab3 = l0.w;
    float a0 = 0.0f, a1 = 0.0f, a2 = 0.0f, a3 = 0.0f;
    __syncthreads();

    const float* base = pred + (size_t)n * CCH * HW + hwb;
    #pragma unroll 4
    for (int c = 0; c < CCH; ++c) {
        float4 v = ((const float4*)(base + (size_t)c * HW))[t];
        const float* row = &ct[c * 20];
        float m0 = row[lab0], m1 = row[lab1], m2 = row[lab2], m3 = row[lab3];
        float d0 = v.x - m0, d1 = v.y - m1, d2 = v.z - m2, d3 = v.w - m3;
        a0 = fmaf(d0, d0, a0);
        a1 = fmaf(d1, d1, a1);
        a2 = fmaf(d2, d2, a2);
        a3 = fmaf(d3, d3, a3);
    }

    const int rep = (t & 3) * KCLS;
    {
        float d, r;
        d = sqrtf(fmaxf(a0, 1e-12f)); r = d - 0.5f; if (r > 0.0f) ldsAdd(&varh[rep + lab0], r * r);
        d = sqrtf(fmaxf(a1, 1e-12f)); r = d - 0.5f; if (r > 0.0f) ldsAdd(&varh[rep + lab1], r * r);
        d = sqrtf(fmaxf(a2, 1e-12f)); r = d - 0.5f; if (r > 0.0f) ldsAdd(&varh[rep + lab2], r * r);
        d = sqrtf(fmaxf(a3, 1e-12f)); r = d - 0.5f; if (r > 0.0f) ldsAdd(&varh[rep + lab3], r * r);
    }
    __syncthreads();
    if (t < KCLS) {
        float s = varh[t] + varh[19 + t] + varh[38 + t] + varh[57 + t];
        unsafeAtomicAdd(&ws[WS_VARSUM + t], s);
    }
}

// ---------------- K4: final combine ----------------
__global__ void k4_final(const float* __restrict__ ws, float* __restrict__ out) {
    const int t = threadIdx.x;   // 64 threads
    float v = 0.0f;
    if (t < KCLS) {
        float c = ws[WS_COUNTS + t];
        if (c > 20.0f) v = ws[WS_VARSUM + t] / fmaxf(c, 1.0f);
    }
    #pragma unroll
    for (int s = 32; s > 0; s >>= 1) v += __shfl_down(v, s);
    if (t == 0) {
        float nv = ws[WS_SCAL + 2];
        out[0] = v / fmaxf(nv, 1.0f) + ws[WS_SCAL + 0] + 0.001f * ws[WS_SCAL + 1];
    }
}

extern "C" void kernel_launch(void* const* d_in, const int* in_sizes, int n_in,
                              void* d_out, int out_size, void* d_ws, size_t ws_size,
                              hipStream_t stream) {
    const float* pred = (const float*)d_in[0];
    const int* tgt = (const int*)d_in[1];
    float* ws = (float*)d_ws;
    float* out = (float*)d_out;

    hipLaunchKernelGGL(k0_zero, dim3(1), dim3(256), 0, stream, ws);
    hipLaunchKernelGGL(k1_sums, dim3(NBLK), dim3(256), 0, stream, pred, tgt, ws);
    hipLaunchKernelGGL(k2_centers, dim3(1), dim3(256), 0, stream, ws);
    hipLaunchKernelGGL(k3_var, dim3(1024), dim3(256), 0, stream, pred, tgt, ws);
    hipLaunchKernelGGL(k4_final, dim3(1), dim3(64), 0, stream, ws, out);
}